// Round 3
// baseline (531.200 us; speedup 1.0000x reference)
//
#include <hip/hip_runtime.h>

// GCN encoder: out = A' relu(A' (x W1) + b1) W2 + b2, A' = D^-1/2 (A+I) D^-1/2
// Round 3: replace random-cursor scatter (105 MB line-granular writebacks) with a
// single-pass multisplit: per-chunk LDS histograms -> hierarchical scan -> scatter
// into per-(chunk,bucket) contiguous ranges. Aggregation = block-per-bucket with
// 8 KB LDS f32 accumulator (ds_add_f32), fused self-loop + dinv + bias/relu.
// Algebra: g = h*dinv  =>  p[d] = dinv[d] * (g[d] + sum_{s->d} g[s]).

#define NN 100000
#define NE 1600000
#define FI 128
#define FH 16
#define CB 128                 // dst-nodes per bucket
#define NB 782                 // ceil(NN/CB)
#define GC 256                 // edge chunks
#define CHUNK 6250             // NE/GC exactly

// ---------- CSR-bucket build ----------
__global__ __launch_bounds__(256) void k_count(const int* __restrict__ dst,
                                               int* __restrict__ hist) {
    __shared__ int h[NB];
    for (int i = threadIdx.x; i < NB; i += 256) h[i] = 0;
    __syncthreads();
    int base = blockIdx.x * CHUNK;
    int end = base + CHUNK; if (end > NE) end = NE;
    for (int i = base + threadIdx.x; i < end; i += 256)
        atomicAdd(&h[dst[i] >> 7], 1);
    __syncthreads();
    for (int b = threadIdx.x; b < NB; b += 256)
        hist[b * GC + blockIdx.x] = h[b];
}

// exclusive scan over chunks within each bucket (one block per bucket)
__global__ __launch_bounds__(256) void k_scan_blocks(int* __restrict__ hist,
                                                     int* __restrict__ totals) {
    __shared__ int s[256];
    int tid = threadIdx.x;
    int v = hist[blockIdx.x * GC + tid];
    s[tid] = v;
    __syncthreads();
    #pragma unroll
    for (int off = 1; off < 256; off <<= 1) {
        int t = (tid >= off) ? s[tid - off] : 0;
        __syncthreads();
        s[tid] += t;
        __syncthreads();
    }
    hist[blockIdx.x * GC + tid] = s[tid] - v;   // exclusive within bucket
    if (tid == 255) totals[blockIdx.x] = s[255];
}

// exclusive scan of bucket totals -> bucketStart (single block)
__global__ __launch_bounds__(1024) void k_scan_buckets(const int* __restrict__ totals,
                                                       int* __restrict__ bucketStart) {
    __shared__ int s[1024];
    int tid = threadIdx.x;
    int v = (tid < NB) ? totals[tid] : 0;
    s[tid] = v;
    __syncthreads();
    #pragma unroll
    for (int off = 1; off < 1024; off <<= 1) {
        int t = (tid >= off) ? s[tid - off] : 0;
        __syncthreads();
        s[tid] += t;
        __syncthreads();
    }
    if (tid < NB) bucketStart[tid] = s[tid] - v;
    if (tid == 0) bucketStart[NB] = NE;
}

__global__ __launch_bounds__(256) void k_addback(int* __restrict__ hist,
                                                 const int* __restrict__ bucketStart) {
    hist[blockIdx.x * GC + threadIdx.x] += bucketStart[blockIdx.x];
}

// scatter: each block's writes to bucket b fall in a private contiguous range
__global__ __launch_bounds__(256) void k_scatter(const int* __restrict__ src,
                                                 const int* __restrict__ dst,
                                                 const int* __restrict__ hist,
                                                 int* __restrict__ packed) {
    __shared__ int cur[NB];
    for (int b = threadIdx.x; b < NB; b += 256)
        cur[b] = hist[b * GC + blockIdx.x];
    __syncthreads();
    int base = blockIdx.x * CHUNK;
    int end = base + CHUNK; if (end > NE) end = NE;
    for (int i = base + threadIdx.x; i < end; i += 256) {
        int d = dst[i];
        int b = d >> 7;
        int pos = atomicAdd(&cur[b], 1);
        packed[pos] = src[i] | ((d & 127) << 17);   // src < 2^17, dl in [0,128)
    }
}

// per-node degree via bucket-local LDS counts -> dinv = rsqrt(deg+1)
__global__ __launch_bounds__(256) void k_deg(const int* __restrict__ packed,
                                             const int* __restrict__ bucketStart,
                                             float* __restrict__ dinv) {
    __shared__ int cnt[CB];
    if (threadIdx.x < CB) cnt[threadIdx.x] = 0;
    __syncthreads();
    int s0 = bucketStart[blockIdx.x], s1 = bucketStart[blockIdx.x + 1];
    for (int i = s0 + threadIdx.x; i < s1; i += 256)
        atomicAdd(&cnt[packed[i] >> 17], 1);
    __syncthreads();
    int node = blockIdx.x * CB + threadIdx.x;
    if (threadIdx.x < CB && node < NN)
        dinv[node] = rsqrtf((float)(cnt[threadIdx.x] + 1));
}

// ---------- dense ops ----------
// g1[n,16] = (x[n,128] @ W1[128,16]) * dinv[n]
__global__ __launch_bounds__(256) void k_gemm1(const float* __restrict__ x,
                                               const float* __restrict__ W1,
                                               const float* __restrict__ dinv,
                                               float* __restrict__ g1) {
    __shared__ __align__(16) float w[FI * FH];
    __shared__ __align__(16) float xs[16 * 132];   // stride 132: no bank alias
    const float4* x4 = (const float4*)x;
    for (int i = threadIdx.x; i < FI * FH / 4; i += 256)
        ((float4*)w)[i] = ((const float4*)W1)[i];
    int nodeBase = blockIdx.x * 16;
    for (int i = threadIdx.x; i < 16 * 32; i += 256) {
        int node = i >> 5, k4 = i & 31;
        int gn = nodeBase + node;
        float4 v = (gn < NN) ? x4[gn * 32 + k4] : float4{0.f, 0.f, 0.f, 0.f};
        *(float4*)&xs[node * 132 + k4 * 4] = v;
    }
    __syncthreads();
    int ln = threadIdx.x >> 4, j = threadIdx.x & 15;
    float acc = 0.f;
    #pragma unroll
    for (int k = 0; k < FI; ++k) acc += xs[ln * 132 + k] * w[k * FH + j];
    int gn = nodeBase + ln;
    if (gn < NN) g1[gn * FH + j] = acc * dinv[gn];
}

// block-per-bucket aggregation with LDS accumulator; fused epilogue.
// RELU=true:  gout = relu(dinv*(gin+acc) + b1) * dinv   (layer-1 -> g2)
// RELU=false: gout = dinv*(gin+acc)                     (layer-2 -> p2)
template<bool RELU>
__global__ __launch_bounds__(256) void k_agg(const int* __restrict__ packed,
                                             const int* __restrict__ bucketStart,
                                             const float* __restrict__ gin,
                                             const float* __restrict__ dinv,
                                             const float* __restrict__ b1,
                                             float* __restrict__ gout) {
    __shared__ float acc[CB * FH];  // 8 KB
    __shared__ float bs[FH];
    for (int i = threadIdx.x; i < CB * FH; i += 256) acc[i] = 0.f;
    if (RELU && threadIdx.x < FH) bs[threadIdx.x] = b1[threadIdx.x];
    __syncthreads();
    int s0 = bucketStart[blockIdx.x], s1 = bucketStart[blockIdx.x + 1];
    int f = threadIdx.x & 15, slot = threadIdx.x >> 4;   // 16 edges in flight/block
    int e = s0 + slot;
    for (; e + 48 < s1; e += 64) {                       // 4x unroll for MLP
        int p0 = packed[e], p1 = packed[e + 16], p2 = packed[e + 32], p3 = packed[e + 48];
        float v0 = gin[(p0 & 131071) * FH + f];
        float v1 = gin[(p1 & 131071) * FH + f];
        float v2 = gin[(p2 & 131071) * FH + f];
        float v3 = gin[(p3 & 131071) * FH + f];
        unsafeAtomicAdd(&acc[(p0 >> 17) * FH + f], v0);
        unsafeAtomicAdd(&acc[(p1 >> 17) * FH + f], v1);
        unsafeAtomicAdd(&acc[(p2 >> 17) * FH + f], v2);
        unsafeAtomicAdd(&acc[(p3 >> 17) * FH + f], v3);
    }
    for (; e < s1; e += 16) {
        int pk = packed[e];
        unsafeAtomicAdd(&acc[(pk >> 17) * FH + f], gin[(pk & 131071) * FH + f]);
    }
    __syncthreads();
    for (int i = threadIdx.x; i < CB * FH; i += 256) {
        int node = blockIdx.x * CB + (i >> 4);
        if (node < NN) {
            float dv = dinv[node];
            float val = dv * (gin[node * FH + (i & 15)] + acc[i]);
            if (RELU) {
                val += bs[i & 15];
                val = val > 0.f ? val : 0.f;
                val *= dv;
            }
            gout[node * FH + (i & 15)] = val;
        }
    }
}

// out[n,128] = p2[n,16] @ W2[16,128] + b2; 16 nodes/block, float4 stores
__global__ __launch_bounds__(256) void k_gemm2(const float* __restrict__ p2,
                                               const float* __restrict__ W2,
                                               const float* __restrict__ b2,
                                               float* __restrict__ out) {
    __shared__ __align__(16) float w[FH * FI];   // 8 KB
    __shared__ float ps[16 * FH];
    __shared__ __align__(16) float bsh[FI];
    for (int i = threadIdx.x; i < FH * FI / 4; i += 256)
        ((float4*)w)[i] = ((const float4*)W2)[i];
    if (threadIdx.x < FI) bsh[threadIdx.x] = b2[threadIdx.x];
    int nodeBase = blockIdx.x * 16;
    {
        int node = threadIdx.x >> 4, k = threadIdx.x & 15;
        int gn = nodeBase + node;
        ps[threadIdx.x] = (gn < NN) ? p2[gn * FH + k] : 0.f;
    }
    __syncthreads();
    int ln = threadIdx.x >> 4;
    float pr[FH];
    #pragma unroll
    for (int k = 0; k < FH; ++k) pr[k] = ps[ln * FH + k];
    int gn = nodeBase + ln;
    if (gn >= NN) return;
    #pragma unroll
    for (int mm = 0; mm < 2; ++mm) {
        int jb = (threadIdx.x & 15) * 4 + 64 * mm;
        float4 a = *(const float4*)&bsh[jb];
        #pragma unroll
        for (int k = 0; k < FH; ++k) {
            float4 wf = *(const float4*)&w[k * FI + jb];
            a.x += pr[k] * wf.x; a.y += pr[k] * wf.y;
            a.z += pr[k] * wf.z; a.w += pr[k] * wf.w;
        }
        *(float4*)&out[gn * FI + jb] = a;
    }
}

extern "C" void kernel_launch(void* const* d_in, const int* in_sizes, int n_in,
                              void* d_out, int out_size, void* d_ws, size_t ws_size,
                              hipStream_t stream) {
    const float* x  = (const float*)d_in[0];
    const int*   ei = (const int*)d_in[1];
    const float* W1 = (const float*)d_in[2];
    const float* b1 = (const float*)d_in[3];
    const float* W2 = (const float*)d_in[4];
    const float* b2 = (const float*)d_in[5];
    float* out = (float*)d_out;

    const int* src = ei;
    const int* dst = ei + NE;

    // workspace (~20.4 MB)
    int*   hist        = (int*)d_ws;             // [NB*GC]
    int*   totals      = hist + NB * GC;         // [NB]
    int*   bucketStart = totals + NB;            // [NB+1]
    int*   packed      = bucketStart + NB + 1;   // [NE]
    float* dinv        = (float*)(packed + NE);  // [NN]
    float* bufA        = dinv + NN;              // [NN*FH]  g1, later p2
    float* bufB        = bufA + NN * FH;         // [NN*FH]  g2

    k_count      <<<GC, 256, 0, stream>>>(dst, hist);
    k_scan_blocks<<<NB, 256, 0, stream>>>(hist, totals);
    k_scan_buckets<<<1, 1024, 0, stream>>>(totals, bucketStart);
    k_addback    <<<NB, 256, 0, stream>>>(hist, bucketStart);
    k_scatter    <<<GC, 256, 0, stream>>>(src, dst, hist, packed);
    k_deg        <<<NB, 256, 0, stream>>>(packed, bucketStart, dinv);

    k_gemm1      <<<(NN + 15) / 16, 256, 0, stream>>>(x, W1, dinv, bufA);
    k_agg<true>  <<<NB, 256, 0, stream>>>(packed, bucketStart, bufA, dinv, b1, bufB);
    k_agg<false> <<<NB, 256, 0, stream>>>(packed, bucketStart, bufB, dinv, b1, bufA);
    k_gemm2      <<<(NN + 15) / 16, 256, 0, stream>>>(bufA, W2, b2, out);
}

// Round 4
// 493.016 us; speedup vs baseline: 1.0775x; 1.0775x over previous
//
#include <hip/hip_runtime.h>

// GCN encoder: out = A' relu(A' (x W1) + b1) W2 + b2, A' = D^-1/2 (A+I) D^-1/2
// Round 4: k_agg was gather-LATENCY bound (434 GB/s eff, VALU 3%, occ 20%).
// Fix MLP: 4 lanes/edge loading float4 (64 lines in flight/wave, was 16),
// CB=64 buckets (1563 blocks -> ~6/CU), XOR-swizzled LDS acc chunks to cut
// ds_add_f32 bank conflicts 8-way -> ~4-way.
// Algebra: g = h*dinv  =>  p[d] = dinv[d] * (g[d] + sum_{s->d} g[s]).

#define NN 100000
#define NE 1600000
#define FI 128
#define FH 16
#define CB 64                  // dst-nodes per bucket
#define NB 1563                // ceil(NN/CB)
#define GC 128                 // edge chunks
#define CHUNK 12500            // NE/GC exactly

// ---------- CSR-bucket build ----------
__global__ __launch_bounds__(256) void k_count(const int* __restrict__ dst,
                                               int* __restrict__ hist) {
    __shared__ int h[NB];
    for (int i = threadIdx.x; i < NB; i += 256) h[i] = 0;
    __syncthreads();
    int base = blockIdx.x * CHUNK;
    int end = base + CHUNK; if (end > NE) end = NE;
    for (int i = base + threadIdx.x; i < end; i += 256)
        atomicAdd(&h[dst[i] >> 6], 1);
    __syncthreads();
    for (int b = threadIdx.x; b < NB; b += 256)
        hist[b * GC + blockIdx.x] = h[b];
}

// exclusive scan over GC chunks within each bucket (one block per bucket)
__global__ __launch_bounds__(GC) void k_scan_blocks(int* __restrict__ hist,
                                                    int* __restrict__ totals) {
    __shared__ int s[GC];
    int tid = threadIdx.x;
    int v = hist[blockIdx.x * GC + tid];
    s[tid] = v;
    __syncthreads();
    #pragma unroll
    for (int off = 1; off < GC; off <<= 1) {
        int t = (tid >= off) ? s[tid - off] : 0;
        __syncthreads();
        s[tid] += t;
        __syncthreads();
    }
    hist[blockIdx.x * GC + tid] = s[tid] - v;   // exclusive within bucket
    if (tid == GC - 1) totals[blockIdx.x] = s[GC - 1];
}

// exclusive scan of NB bucket totals (single block, 2 elems/thread)
__global__ __launch_bounds__(1024) void k_scan_buckets(const int* __restrict__ totals,
                                                       int* __restrict__ bucketStart) {
    __shared__ int s[1024];
    int tid = threadIdx.x;
    int i0 = 2 * tid, i1 = 2 * tid + 1;
    int a = (i0 < NB) ? totals[i0] : 0;
    int b = (i1 < NB) ? totals[i1] : 0;
    s[tid] = a + b;
    __syncthreads();
    #pragma unroll
    for (int off = 1; off < 1024; off <<= 1) {
        int t = (tid >= off) ? s[tid - off] : 0;
        __syncthreads();
        s[tid] += t;
        __syncthreads();
    }
    int excl = s[tid] - (a + b);
    if (i0 < NB) bucketStart[i0] = excl;
    if (i1 < NB) bucketStart[i1] = excl + a;
    if (tid == 0) bucketStart[NB] = NE;
}

__global__ __launch_bounds__(GC) void k_addback(int* __restrict__ hist,
                                                const int* __restrict__ bucketStart) {
    hist[blockIdx.x * GC + threadIdx.x] += bucketStart[blockIdx.x];
}

// scatter: each block's writes to bucket b fill a private contiguous range
__global__ __launch_bounds__(256) void k_scatter(const int* __restrict__ src,
                                                 const int* __restrict__ dst,
                                                 const int* __restrict__ hist,
                                                 int* __restrict__ packed) {
    __shared__ int cur[NB];
    for (int b = threadIdx.x; b < NB; b += 256)
        cur[b] = hist[b * GC + blockIdx.x];
    __syncthreads();
    int base = blockIdx.x * CHUNK;
    int end = base + CHUNK; if (end > NE) end = NE;
    for (int i = base + threadIdx.x; i < end; i += 256) {
        int d = dst[i];
        int b = d >> 6;
        int pos = atomicAdd(&cur[b], 1);
        packed[pos] = src[i] | ((d & 63) << 17);   // src < 2^17, dl in [0,64)
    }
}

// per-node degree via bucket-local LDS counts -> dinv = rsqrt(deg+1)
__global__ __launch_bounds__(256) void k_deg(const int* __restrict__ packed,
                                             const int* __restrict__ bucketStart,
                                             float* __restrict__ dinv) {
    __shared__ int cnt[CB];
    if (threadIdx.x < CB) cnt[threadIdx.x] = 0;
    __syncthreads();
    int s0 = bucketStart[blockIdx.x], s1 = bucketStart[blockIdx.x + 1];
    for (int i = s0 + threadIdx.x; i < s1; i += 256)
        atomicAdd(&cnt[packed[i] >> 17], 1);
    __syncthreads();
    int node = blockIdx.x * CB + threadIdx.x;
    if (threadIdx.x < CB && node < NN)
        dinv[node] = rsqrtf((float)(cnt[threadIdx.x] + 1));
}

// ---------- dense ops ----------
// g1[n,16] = (x[n,128] @ W1[128,16]) * dinv[n]
__global__ __launch_bounds__(256) void k_gemm1(const float* __restrict__ x,
                                               const float* __restrict__ W1,
                                               const float* __restrict__ dinv,
                                               float* __restrict__ g1) {
    __shared__ __align__(16) float w[FI * FH];
    __shared__ __align__(16) float xs[16 * 132];   // stride 132: no bank alias
    const float4* x4 = (const float4*)x;
    for (int i = threadIdx.x; i < FI * FH / 4; i += 256)
        ((float4*)w)[i] = ((const float4*)W1)[i];
    int nodeBase = blockIdx.x * 16;
    for (int i = threadIdx.x; i < 16 * 32; i += 256) {
        int node = i >> 5, k4 = i & 31;
        int gn = nodeBase + node;
        float4 v = (gn < NN) ? x4[gn * 32 + k4] : float4{0.f, 0.f, 0.f, 0.f};
        *(float4*)&xs[node * 132 + k4 * 4] = v;
    }
    __syncthreads();
    int ln = threadIdx.x >> 4, j = threadIdx.x & 15;
    float acc = 0.f;
    #pragma unroll
    for (int k = 0; k < FI; ++k) acc += xs[ln * 132 + k] * w[k * FH + j];
    int gn = nodeBase + ln;
    if (gn < NN) g1[gn * FH + j] = acc * dinv[gn];
}

// block-per-bucket aggregation; 4 lanes/edge each gathering a float4.
// acc chunk XOR-swizzled by node-local to cut ds_add bank conflicts.
// RELU=true:  gout = relu(dinv*(gin+acc) + b1) * dinv   (layer-1 -> g2)
// RELU=false: gout = dinv*(gin+acc)                     (layer-2 -> p2)
template<bool RELU>
__global__ __launch_bounds__(256) void k_agg(const int* __restrict__ packed,
                                             const int* __restrict__ bucketStart,
                                             const float* __restrict__ gin,
                                             const float* __restrict__ dinv,
                                             const float* __restrict__ b1,
                                             float* __restrict__ gout) {
    __shared__ __align__(16) float acc[CB * FH];   // 4 KB
    ((float4*)acc)[threadIdx.x] = float4{0.f, 0.f, 0.f, 0.f};
    __syncthreads();
    int s0 = bucketStart[blockIdx.x], s1 = bucketStart[blockIdx.x + 1];
    int c = threadIdx.x & 3;            // float4 chunk 0..3
    int slot = threadIdx.x >> 2;        // 64 edge slots
    int e = s0 + slot;
    for (; e + 192 < s1; e += 256) {    // 256 edges in flight per block
        int p0 = packed[e], p1 = packed[e + 64], p2 = packed[e + 128], p3 = packed[e + 192];
        float4 v0 = *(const float4*)&gin[(p0 & 131071) * FH + c * 4];
        float4 v1 = *(const float4*)&gin[(p1 & 131071) * FH + c * 4];
        float4 v2 = *(const float4*)&gin[(p2 & 131071) * FH + c * 4];
        float4 v3 = *(const float4*)&gin[(p3 & 131071) * FH + c * 4];
        int d0 = p0 >> 17, d1 = p1 >> 17, d2 = p2 >> 17, d3 = p3 >> 17;
        int a0 = d0 * FH + ((c ^ d0) & 3) * 4;
        int a1 = d1 * FH + ((c ^ d1) & 3) * 4;
        int a2 = d2 * FH + ((c ^ d2) & 3) * 4;
        int a3 = d3 * FH + ((c ^ d3) & 3) * 4;
        unsafeAtomicAdd(&acc[a0 + 0], v0.x); unsafeAtomicAdd(&acc[a0 + 1], v0.y);
        unsafeAtomicAdd(&acc[a0 + 2], v0.z); unsafeAtomicAdd(&acc[a0 + 3], v0.w);
        unsafeAtomicAdd(&acc[a1 + 0], v1.x); unsafeAtomicAdd(&acc[a1 + 1], v1.y);
        unsafeAtomicAdd(&acc[a1 + 2], v1.z); unsafeAtomicAdd(&acc[a1 + 3], v1.w);
        unsafeAtomicAdd(&acc[a2 + 0], v2.x); unsafeAtomicAdd(&acc[a2 + 1], v2.y);
        unsafeAtomicAdd(&acc[a2 + 2], v2.z); unsafeAtomicAdd(&acc[a2 + 3], v2.w);
        unsafeAtomicAdd(&acc[a3 + 0], v3.x); unsafeAtomicAdd(&acc[a3 + 1], v3.y);
        unsafeAtomicAdd(&acc[a3 + 2], v3.z); unsafeAtomicAdd(&acc[a3 + 3], v3.w);
    }
    for (; e < s1; e += 64) {
        int pk = packed[e];
        float4 v = *(const float4*)&gin[(pk & 131071) * FH + c * 4];
        int dl = pk >> 17;
        int a = dl * FH + ((c ^ dl) & 3) * 4;
        unsafeAtomicAdd(&acc[a + 0], v.x); unsafeAtomicAdd(&acc[a + 1], v.y);
        unsafeAtomicAdd(&acc[a + 2], v.z); unsafeAtomicAdd(&acc[a + 3], v.w);
    }
    __syncthreads();
    // epilogue: thread -> (node_local = tid>>2, chunk = tid&3)
    int nl = threadIdx.x >> 2;
    int node = blockIdx.x * CB + nl;
    if (node < NN) {
        float dv = dinv[node];
        float4 a = *(float4*)&acc[nl * FH + ((c ^ nl) & 3) * 4];
        float4 gi = *(const float4*)&gin[node * FH + c * 4];
        float4 val;
        val.x = dv * (gi.x + a.x); val.y = dv * (gi.y + a.y);
        val.z = dv * (gi.z + a.z); val.w = dv * (gi.w + a.w);
        if (RELU) {
            float4 bb = *(const float4*)&b1[c * 4];
            val.x = fmaxf(val.x + bb.x, 0.f) * dv;
            val.y = fmaxf(val.y + bb.y, 0.f) * dv;
            val.z = fmaxf(val.z + bb.z, 0.f) * dv;
            val.w = fmaxf(val.w + bb.w, 0.f) * dv;
        }
        *(float4*)&gout[node * FH + c * 4] = val;
    }
}

// out[n,128] = p2[n,16] @ W2[16,128] + b2; 16 nodes/block, float4 stores
__global__ __launch_bounds__(256) void k_gemm2(const float* __restrict__ p2,
                                               const float* __restrict__ W2,
                                               const float* __restrict__ b2,
                                               float* __restrict__ out) {
    __shared__ __align__(16) float w[FH * FI];
    __shared__ float ps[16 * FH];
    __shared__ __align__(16) float bsh[FI];
    for (int i = threadIdx.x; i < FH * FI / 4; i += 256)
        ((float4*)w)[i] = ((const float4*)W2)[i];
    if (threadIdx.x < FI) bsh[threadIdx.x] = b2[threadIdx.x];
    int nodeBase = blockIdx.x * 16;
    {
        int node = threadIdx.x >> 4, k = threadIdx.x & 15;
        int gn = nodeBase + node;
        ps[threadIdx.x] = (gn < NN) ? p2[gn * FH + k] : 0.f;
    }
    __syncthreads();
    int ln = threadIdx.x >> 4;
    float pr[FH];
    #pragma unroll
    for (int k = 0; k < FH; ++k) pr[k] = ps[ln * FH + k];
    int gn = nodeBase + ln;
    if (gn >= NN) return;
    #pragma unroll
    for (int mm = 0; mm < 2; ++mm) {
        int jb = (threadIdx.x & 15) * 4 + 64 * mm;
        float4 a = *(const float4*)&bsh[jb];
        #pragma unroll
        for (int k = 0; k < FH; ++k) {
            float4 wf = *(const float4*)&w[k * FI + jb];
            a.x += pr[k] * wf.x; a.y += pr[k] * wf.y;
            a.z += pr[k] * wf.z; a.w += pr[k] * wf.w;
        }
        *(float4*)&out[gn * FI + jb] = a;
    }
}

extern "C" void kernel_launch(void* const* d_in, const int* in_sizes, int n_in,
                              void* d_out, int out_size, void* d_ws, size_t ws_size,
                              hipStream_t stream) {
    const float* x  = (const float*)d_in[0];
    const int*   ei = (const int*)d_in[1];
    const float* W1 = (const float*)d_in[2];
    const float* b1 = (const float*)d_in[3];
    const float* W2 = (const float*)d_in[4];
    const float* b2 = (const float*)d_in[5];
    float* out = (float*)d_out;

    const int* src = ei;
    const int* dst = ei + NE;

    // workspace (~20.5 MB)
    int*   hist        = (int*)d_ws;             // [NB*GC]
    int*   totals      = hist + NB * GC;         // [NB]
    int*   bucketStart = totals + NB;            // [NB+1]
    int*   packed      = bucketStart + NB + 1;   // [NE]
    float* dinv        = (float*)(packed + NE);  // [NN]
    float* bufA        = dinv + NN;              // [NN*FH]  g1, later p2
    float* bufB        = bufA + NN * FH;         // [NN*FH]  g2

    k_count       <<<GC, 256, 0, stream>>>(dst, hist);
    k_scan_blocks <<<NB, GC, 0, stream>>>(hist, totals);
    k_scan_buckets<<<1, 1024, 0, stream>>>(totals, bucketStart);
    k_addback     <<<NB, GC, 0, stream>>>(hist, bucketStart);
    k_scatter     <<<GC, 256, 0, stream>>>(src, dst, hist, packed);
    k_deg         <<<NB, 256, 0, stream>>>(packed, bucketStart, dinv);

    k_gemm1       <<<(NN + 15) / 16, 256, 0, stream>>>(x, W1, dinv, bufA);
    k_agg<true>   <<<NB, 256, 0, stream>>>(packed, bucketStart, bufA, dinv, b1, bufB);
    k_agg<false>  <<<NB, 256, 0, stream>>>(packed, bucketStart, bufB, dinv, b1, bufA);
    k_gemm2       <<<(NN + 15) / 16, 256, 0, stream>>>(bufA, W2, b2, out);
}